// Round 10
// baseline (964.609 us; speedup 1.0000x reference)
//
#include <hip/hip_runtime.h>
#include <hip/hip_cooperative_groups.h>

namespace cg = cooperative_groups;

#define NN 50000
#define NE 800000
#define IN_C 256
#define HID_C 256
#define OUT_C 128
#define NB 196        // ceil(NN/256)
#define NEB 391       // ceil(NE/(8*256))
#define G1TILES 782   // (HID_C/128) * ceil(NN/128)
#define G2TILES 391   // (OUT_C/128) * ceil(NN/128)
#define GRID 768      // 3 blocks/CU x 256 CUs (LDS 41KB -> 3/CU; launch_bounds caps VGPR)

typedef unsigned short u16;
typedef __attribute__((ext_vector_type(8))) short short8;
typedef __attribute__((ext_vector_type(8))) unsigned short ushort8;
typedef __attribute__((ext_vector_type(4))) float f32x4;

__device__ __forceinline__ u16 f2b(float f) {
  unsigned int u = __float_as_uint(f);
  return (u16)((u + 0x7FFFu + ((u >> 16) & 1u)) >> 16);  // RNE
}
__device__ __forceinline__ float b2f(u16 s) {
  return __uint_as_float(((unsigned int)s) << 16);
}

// ---------------- MFMA GEMM body, row-scaled epilogue ----------------
// C[r,:]bf16 = dscale[r] * (A[r,:] @ Bt^T).  BM=BN=128, BK=32, 4 waves 2x2,
// register prefetch + double-buffered LDS, one barrier per K-iter.

template <bool A_IS_F32>
__device__ __forceinline__ void gemm_body(const void* __restrict__ Ap,
                                          const u16* __restrict__ Bt,
                                          const float* __restrict__ dscale,
                                          u16* __restrict__ C, int M, int N,
                                          int bx, int by,
                                          u16 (&Asl)[2][5120], u16 (&Bsl)[2][5120]) {
  const int tid = threadIdx.x;
  const int row0 = by * 128;
  const int col0 = bx * 128;

  f32x4 acc[4][4] = {};

  const int seg = tid & 7;
  const int rb = tid >> 3;
  const int wave = tid >> 6, lane = tid & 63;
  const int wm = wave >> 1, wn = wave & 1;
  const int qr = lane & 15, quad = lane >> 4;

  float4 aF[4];
  ushort4 aU[4];
  ushort4 bR[4];

  auto load_tiles = [&](int k0) {
    if constexpr (A_IS_F32) {
      const float* A = (const float*)Ap;
#pragma unroll
      for (int i = 0; i < 4; ++i) {
        int gr = row0 + rb + i * 32;
        aF[i] = (gr < M) ? *(const float4*)&A[(size_t)gr * 256 + k0 + seg * 4]
                         : make_float4(0.f, 0.f, 0.f, 0.f);
      }
    } else {
      const u16* A = (const u16*)Ap;
#pragma unroll
      for (int i = 0; i < 4; ++i) {
        int gr = row0 + rb + i * 32;
        aU[i] = (gr < M) ? *(const ushort4*)&A[(size_t)gr * 256 + k0 + seg * 4]
                         : make_ushort4(0, 0, 0, 0);
      }
    }
#pragma unroll
    for (int i = 0; i < 4; ++i) {
      int n = rb + i * 32;
      bR[i] = *(const ushort4*)&Bt[(size_t)(col0 + n) * 256 + k0 + seg * 4];
    }
  };

  auto write_lds = [&](int buf) {
#pragma unroll
    for (int i = 0; i < 4; ++i) {
      int r = rb + i * 32;
      ushort4 u;
      if constexpr (A_IS_F32) {
        u.x = f2b(aF[i].x); u.y = f2b(aF[i].y);
        u.z = f2b(aF[i].z); u.w = f2b(aF[i].w);
      } else {
        u = aU[i];
      }
      *(ushort4*)&Asl[buf][r * 40 + seg * 4] = u;
      *(ushort4*)&Bsl[buf][r * 40 + seg * 4] = bR[i];
    }
  };

  load_tiles(0);
  write_lds(0);
  __syncthreads();

#pragma unroll
  for (int it = 0; it < 8; ++it) {
    const int cur = it & 1;
    if (it < 7) load_tiles((it + 1) * 32);

    short8 afr[4], bfr[4];
#pragma unroll
    for (int mt = 0; mt < 4; ++mt)
      afr[mt] = *(const short8*)&Asl[cur][(wm * 64 + mt * 16 + qr) * 40 + quad * 8];
#pragma unroll
    for (int nt = 0; nt < 4; ++nt)
      bfr[nt] = *(const short8*)&Bsl[cur][(wn * 64 + nt * 16 + qr) * 40 + quad * 8];
#pragma unroll
    for (int mt = 0; mt < 4; ++mt)
#pragma unroll
      for (int nt = 0; nt < 4; ++nt)
        acc[mt][nt] = __builtin_amdgcn_mfma_f32_16x16x32_bf16(afr[mt], bfr[nt], acc[mt][nt], 0, 0, 0);

    if (it < 7) {
      write_lds(1 - cur);
      __syncthreads();
    }
  }

#pragma unroll
  for (int mt = 0; mt < 4; ++mt) {
#pragma unroll
    for (int i = 0; i < 4; ++i) {
      int gr = row0 + wm * 64 + mt * 16 + quad * 4 + i;
      if (gr < M) {
        float sc = dscale[gr];
#pragma unroll
        for (int nt = 0; nt < 4; ++nt) {
          int gc = col0 + wn * 64 + nt * 16 + qr;
          C[(size_t)gr * N + gc] = f2b(acc[mt][nt][i] * sc);
        }
      }
    }
  }
}

// ---------------- aggregation bodies: weightless sum of pre-scaled rows ----------------
// out[v] = dinv[v] * (sum_{src in N(v)} Hs[src] + Hs[v]) + bias   (+ relu for 256)

__device__ __forceinline__ void agg256_body(int blk, const u16* __restrict__ h,
                                            const int* __restrict__ row_off,
                                            const int* __restrict__ csr,
                                            const float* __restrict__ dinv,
                                            const float* __restrict__ bias,
                                            u16* __restrict__ out) {
  int wave = threadIdx.x >> 6;
  int lane = threadIdx.x & 63;
  int half = lane >> 5;
  int sl = lane & 31;
  int v = blk * 8 + wave * 2 + half;
  if (v >= NN) return;
  int beg = row_off[v], end = row_off[v + 1];
  float a[8] = {};
  int e = beg;
  for (; e < end && (e & 3); ++e) {
    int s0 = csr[e];
    ushort8 g0 = *(const ushort8*)&h[(size_t)s0 * 256 + sl * 8];
#pragma unroll
    for (int i = 0; i < 8; ++i) a[i] += b2f((u16)g0[i]);
  }
  for (; e + 7 < end; e += 8) {
    int4 i0 = *(const int4*)&csr[e];
    int4 i1 = *(const int4*)&csr[e + 4];
    int s[8] = {i0.x, i0.y, i0.z, i0.w, i1.x, i1.y, i1.z, i1.w};
    ushort8 g[8];
#pragma unroll
    for (int j = 0; j < 8; ++j)
      g[j] = *(const ushort8*)&h[(size_t)s[j] * 256 + sl * 8];
#pragma unroll
    for (int j = 0; j < 8; ++j)
#pragma unroll
      for (int i = 0; i < 8; ++i) a[i] += b2f((u16)g[j][i]);
  }
  for (; e < end; ++e) {
    int s0 = csr[e];
    ushort8 g0 = *(const ushort8*)&h[(size_t)s0 * 256 + sl * 8];
#pragma unroll
    for (int i = 0; i < 8; ++i) a[i] += b2f((u16)g0[i]);
  }
  ushort8 hs = *(const ushort8*)&h[(size_t)v * 256 + sl * 8];
#pragma unroll
  for (int i = 0; i < 8; ++i) a[i] += b2f((u16)hs[i]);
  float dv = dinv[v];
  float4 bv0 = *(const float4*)&bias[sl * 8];
  float4 bv1 = *(const float4*)&bias[sl * 8 + 4];
  float bb[8] = {bv0.x, bv0.y, bv0.z, bv0.w, bv1.x, bv1.y, bv1.z, bv1.w};
  ushort8 o;
#pragma unroll
  for (int i = 0; i < 8; ++i) {
    float r = fmaxf(a[i] * dv + bb[i], 0.f);
    o[i] = (short)f2b(r);
  }
  *(ushort8*)&out[(size_t)v * 256 + sl * 8] = o;
}

__device__ __forceinline__ void agg128_body(int blk, const u16* __restrict__ h,
                                            const int* __restrict__ row_off,
                                            const int* __restrict__ csr,
                                            const float* __restrict__ dinv,
                                            const float* __restrict__ bias,
                                            float* __restrict__ out) {
  int wave = threadIdx.x >> 6;
  int lane = threadIdx.x & 63;
  int quarter = lane >> 4;
  int sl = lane & 15;
  int v = blk * 16 + wave * 4 + quarter;
  if (v >= NN) return;
  int beg = row_off[v], end = row_off[v + 1];
  float a[8] = {};
  int e = beg;
  for (; e < end && (e & 3); ++e) {
    int s0 = csr[e];
    ushort8 g0 = *(const ushort8*)&h[(size_t)s0 * 128 + sl * 8];
#pragma unroll
    for (int i = 0; i < 8; ++i) a[i] += b2f((u16)g0[i]);
  }
  for (; e + 7 < end; e += 8) {
    int4 i0 = *(const int4*)&csr[e];
    int4 i1 = *(const int4*)&csr[e + 4];
    int s[8] = {i0.x, i0.y, i0.z, i0.w, i1.x, i1.y, i1.z, i1.w};
    ushort8 g[8];
#pragma unroll
    for (int j = 0; j < 8; ++j)
      g[j] = *(const ushort8*)&h[(size_t)s[j] * 128 + sl * 8];
#pragma unroll
    for (int j = 0; j < 8; ++j)
#pragma unroll
      for (int i = 0; i < 8; ++i) a[i] += b2f((u16)g[j][i]);
  }
  for (; e < end; ++e) {
    int s0 = csr[e];
    ushort8 g0 = *(const ushort8*)&h[(size_t)s0 * 128 + sl * 8];
#pragma unroll
    for (int i = 0; i < 8; ++i) a[i] += b2f((u16)g0[i]);
  }
  ushort8 hs = *(const ushort8*)&h[(size_t)v * 128 + sl * 8];
#pragma unroll
  for (int i = 0; i < 8; ++i) a[i] += b2f((u16)hs[i]);
  float dv = dinv[v];
  float4 bv0 = *(const float4*)&bias[sl * 8];
  float4 bv1 = *(const float4*)&bias[sl * 8 + 4];
  float bb[8] = {bv0.x, bv0.y, bv0.z, bv0.w, bv1.x, bv1.y, bv1.z, bv1.w};
  float o[8];
#pragma unroll
  for (int i = 0; i < 8; ++i) o[i] = a[i] * dv + bb[i];
  *(float4*)&out[(size_t)v * 128 + sl * 8] = make_float4(o[0], o[1], o[2], o[3]);
  *(float4*)&out[(size_t)v * 128 + sl * 8 + 4] = make_float4(o[4], o[5], o[6], o[7]);
}

// ---------------- persistent cooperative mega-kernel ----------------

struct MegaParams {
  const float* W1; const float* W2;
  u16* W1t; u16* W2t;
  const int* row; const int* col;
  int* cnt; int* bsum; int* row_off; int* cursor; float* dinv; int* csr;
  const float* x; u16* Hb;
  const float* b1; u16* H2b;
  u16* H3b;
  const float* b2; float* out;
};

__global__ __launch_bounds__(256, 3) void mega(MegaParams p) {
  cg::grid_group grid = cg::this_grid();
  __shared__ u16 Asl[2][5120];
  __shared__ u16 Bsl[2][5120];
  __shared__ int sA[4], sB[5], sC[4];
  const int b = blockIdx.x;
  const int t = threadIdx.x;
  const int lane = t & 63, wid = t >> 6;

  // ---- P0: weight convert + cnt zero ----
  if (b < 256) {
    int id = b * 256 + t;
    int n = id >> 8, k = id & 255;
    p.W1t[id] = f2b(p.W1[k * 256 + n]);
    if (id < 128 * 256) p.W2t[id] = f2b(p.W2[k * 128 + n]);
  } else if (b < 256 + NB) {
    int i = (b - 256) * 256 + t;
    if (i < NN) p.cnt[i] = 0;
  }
  grid.sync();

  // ---- P1: degree histogram (grid-stride) ----
  for (int e = b * 256 + t; e < NE; e += GRID * 256)
    atomicAdd(&p.cnt[p.col[e]], 1);
  grid.sync();

  // ---- P2: per-chunk sums ----
  if (b < NB) {
    int i = b * 256 + t;
    int v = (i < NN) ? p.cnt[i] : 0;
#pragma unroll
    for (int off = 32; off > 0; off >>= 1) v += __shfl_down(v, off, 64);
    if (lane == 0) sA[wid] = v;
    __syncthreads();
    if (t == 0) p.bsum[b] = sA[0] + sA[1] + sA[2] + sA[3];
  }
  grid.sync();

  // ---- P3: exclusive scan -> row_off/cursor/dinv ----
  if (b < NB) {
    int bv = (t < b) ? p.bsum[t] : 0;
#pragma unroll
    for (int off = 32; off > 0; off >>= 1) bv += __shfl_down(bv, off, 64);
    if (lane == 0) sC[wid] = bv;
    __syncthreads();
    int boffs = sC[0] + sC[1] + sC[2] + sC[3];
    int i = b * 256 + t;
    int v = (i < NN) ? p.cnt[i] : 0;
    int s = v;
#pragma unroll
    for (int off = 1; off < 64; off <<= 1) {
      int tt = __shfl_up(s, off, 64);
      if (lane >= off) s += tt;
    }
    if (lane == 63) sA[wid] = s;
    __syncthreads();
    if (t == 0) {
      int acc = 0;
#pragma unroll
      for (int w = 0; w < 4; ++w) { sB[w] = acc; acc += sA[w]; }
    }
    __syncthreads();
    if (i < NN) {
      int off = boffs + sB[wid] + (s - v);
      p.row_off[i] = off;
      p.cursor[i] = off;
      p.dinv[i] = rsqrtf((float)(v + 1));
    }
    if (b == 0 && t == 0) p.row_off[NN] = NE;
  }
  grid.sync();

  // ---- P4: scatter (units 0..NEB) + GEMM1 (units NEB..NEB+G1TILES) ----
  for (int u = b; u < NEB + G1TILES; u += GRID) {
    if (u < NEB) {
      const int T = NEB * 256;
      int idx = u * 256 + t;
#pragma unroll
      for (int i = 0; i < 8; ++i) {
        int e = idx + i * T;
        if (e < NE) {
          int c = p.col[e];
          int pos = atomicAdd(&p.cursor[c], 1);
          __builtin_nontemporal_store(p.row[e], &p.csr[pos]);
        }
      }
    } else {
      int gb = u - NEB;
      gemm_body<true>(p.x, p.W1t, p.dinv, p.Hb, NN, HID_C, gb & 1, gb >> 1, Asl, Bsl);
    }
  }
  grid.sync();

  // ---- P5: agg256 ----
  for (int u = b; u < (NN + 7) / 8; u += GRID)
    agg256_body(u, p.Hb, p.row_off, p.csr, p.dinv, p.b1, p.H2b);
  grid.sync();

  // ---- P6: GEMM2 ----
  for (int u = b; u < G2TILES; u += GRID)
    gemm_body<false>(p.H2b, p.W2t, p.dinv, p.H3b, NN, OUT_C, 0, u, Asl, Bsl);
  grid.sync();

  // ---- P7: agg128 ----
  for (int u = b; u < (NN + 15) / 16; u += GRID)
    agg128_body(u, p.H3b, p.row_off, p.csr, p.dinv, p.b2, p.out);
}

// ---------------- fallback kernels (round-8 structure, known-good) ----------------

__global__ __launch_bounds__(256) void convw_hist(const float* __restrict__ W1,
                                                  const float* __restrict__ W2,
                                                  u16* __restrict__ W1t,
                                                  u16* __restrict__ W2t,
                                                  const int* __restrict__ col,
                                                  int* __restrict__ cnt) {
  int b = blockIdx.x;
  if (b < 256) {
    int id = b * 256 + threadIdx.x;
    int n = id >> 8, k = id & 255;
    W1t[id] = f2b(W1[k * 256 + n]);
    if (id < 128 * 256) W2t[id] = f2b(W2[k * 128 + n]);
  } else {
    const int T = NEB * 256;
    int idx = (b - 256) * 256 + threadIdx.x;
#pragma unroll
    for (int i = 0; i < 8; ++i) {
      int e = idx + i * T;
      if (e < NE) atomicAdd(&cnt[col[e]], 1);
    }
  }
}

__global__ __launch_bounds__(256) void scan1_kernel(const int* __restrict__ cnt,
                                                    int* __restrict__ bsum) {
  __shared__ int ws[4];
  int i = blockIdx.x * 256 + threadIdx.x;
  int lane = threadIdx.x & 63, wid = threadIdx.x >> 6;
  int v = (i < NN) ? cnt[i] : 0;
#pragma unroll
  for (int off = 32; off > 0; off >>= 1) v += __shfl_down(v, off, 64);
  if (lane == 0) ws[wid] = v;
  __syncthreads();
  if (threadIdx.x == 0) bsum[blockIdx.x] = ws[0] + ws[1] + ws[2] + ws[3];
}

__global__ __launch_bounds__(256) void scan23_kernel(const int* __restrict__ cnt,
                                                     const int* __restrict__ bsum,
                                                     int* __restrict__ row_off,
                                                     int* __restrict__ cursor,
                                                     float* __restrict__ dinv) {
  __shared__ int ws2[4], wsum[4], wpre[4];
  int b = blockIdx.x, t = threadIdx.x;
  int lane = t & 63, wid = t >> 6;
  int bv = (t < b) ? bsum[t] : 0;
#pragma unroll
  for (int off = 32; off > 0; off >>= 1) bv += __shfl_down(bv, off, 64);
  if (lane == 0) ws2[wid] = bv;
  __syncthreads();
  int boffs = ws2[0] + ws2[1] + ws2[2] + ws2[3];
  int i = b * 256 + t;
  int v = (i < NN) ? cnt[i] : 0;
  int s = v;
#pragma unroll
  for (int off = 1; off < 64; off <<= 1) {
    int tt = __shfl_up(s, off, 64);
    if (lane >= off) s += tt;
  }
  if (lane == 63) wsum[wid] = s;
  __syncthreads();
  if (t == 0) {
    int acc = 0;
#pragma unroll
    for (int w = 0; w < 4; ++w) { wpre[w] = acc; acc += wsum[w]; }
  }
  __syncthreads();
  if (i < NN) {
    int off = boffs + wpre[wid] + (s - v);
    row_off[i] = off;
    cursor[i] = off;
    dinv[i] = rsqrtf((float)(v + 1));
  }
  if (b == 0 && t == 0) row_off[NN] = NE;
}

__global__ __launch_bounds__(256) void gemm1_scatter(const float* __restrict__ x,
                                                     const u16* __restrict__ W1t,
                                                     const float* __restrict__ dinv,
                                                     u16* __restrict__ Hb, int ngb,
                                                     const int* __restrict__ row,
                                                     const int* __restrict__ col,
                                                     int* __restrict__ cursor,
                                                     int* __restrict__ csr) {
  __shared__ u16 Asl[2][5120];
  __shared__ u16 Bsl[2][5120];
  int b = blockIdx.x;
  if (b < ngb) {
    gemm_body<true>(x, W1t, dinv, Hb, NN, HID_C, b & 1, b >> 1, Asl, Bsl);
  } else {
    const int T = NEB * 256;
    int idx = (b - ngb) * 256 + threadIdx.x;
#pragma unroll
    for (int i = 0; i < 8; ++i) {
      int e = idx + i * T;
      if (e < NE) {
        int c = col[e];
        int p = atomicAdd(&cursor[c], 1);
        __builtin_nontemporal_store(row[e], &csr[p]);
      }
    }
  }
}

__global__ __launch_bounds__(256) void gemm_mfma2(const u16* __restrict__ Ap,
                                                  const u16* __restrict__ Bt,
                                                  const float* __restrict__ dinv,
                                                  u16* __restrict__ C) {
  __shared__ u16 Asl[2][5120];
  __shared__ u16 Bsl[2][5120];
  gemm_body<false>(Ap, Bt, dinv, C, NN, OUT_C, blockIdx.x, blockIdx.y, Asl, Bsl);
}

__global__ __launch_bounds__(256) void agg256_bf(const u16* __restrict__ h,
                                                 const int* __restrict__ row_off,
                                                 const int* __restrict__ csr,
                                                 const float* __restrict__ dinv,
                                                 const float* __restrict__ bias,
                                                 u16* __restrict__ out) {
  agg256_body(blockIdx.x, h, row_off, csr, dinv, bias, out);
}

__global__ __launch_bounds__(256) void agg128_bf(const u16* __restrict__ h,
                                                 const int* __restrict__ row_off,
                                                 const int* __restrict__ csr,
                                                 const float* __restrict__ dinv,
                                                 const float* __restrict__ bias,
                                                 float* __restrict__ out) {
  agg128_body(blockIdx.x, h, row_off, csr, dinv, bias, out);
}

// ---------------- launch ----------------

extern "C" void kernel_launch(void* const* d_in, const int* in_sizes, int n_in,
                              void* d_out, int out_size, void* d_ws, size_t ws_size,
                              hipStream_t stream) {
  const float* x = (const float*)d_in[0];
  const int* ei = (const int*)d_in[1];
  const float* W1 = (const float*)d_in[2];
  const float* b1 = (const float*)d_in[3];
  const float* W2 = (const float*)d_in[4];
  const float* b2 = (const float*)d_in[5];
  float* out = (float*)d_out;

  const int* row = ei;
  const int* col = ei + NE;

  // workspace layout — all segments 16B-multiples so csr stays 16B-aligned
  u16* Hb = (u16*)d_ws;                       // [NN,256] bf16, pre-scaled by dinv[row]
  u16* H2b = Hb + (size_t)NN * 256;           // [NN,256] bf16
  u16* H3b = H2b + (size_t)NN * 256;          // [NN,128] bf16, pre-scaled
  u16* W1t = H3b + (size_t)NN * 128;          // [256,256] bf16
  u16* W2t = W1t + 256 * 256;                 // [128,256] bf16
  int* cnt = (int*)(W2t + 128 * 256);         // [NN]
  int* row_off = cnt + NN;                    // [NN+4]
  int* cursor = row_off + NN + 4;             // [NN]
  float* dinv = (float*)(cursor + NN);        // [NN]
  int* bsum = (int*)(dinv + NN);              // [256]
  int* csr = bsum + 256;                      // [NE] src only, 16B-aligned

  MegaParams p;
  p.W1 = W1; p.W2 = W2; p.W1t = W1t; p.W2t = W2t;
  p.row = row; p.col = col;
  p.cnt = cnt; p.bsum = bsum; p.row_off = row_off; p.cursor = cursor;
  p.dinv = dinv; p.csr = csr;
  p.x = x; p.Hb = Hb; p.b1 = b1; p.H2b = H2b; p.H3b = H3b; p.b2 = b2; p.out = out;

  void* args[] = {(void*)&p};
  hipError_t err = hipLaunchCooperativeKernel((const void*)mega, dim3(GRID), dim3(256),
                                              args, 0, stream);
  if (err != hipSuccess) {
    // fallback: round-8 multi-launch pipeline (known-good ~304 us)
    (void)hipGetLastError();
    hipMemsetAsync(cnt, 0, NN * sizeof(int), stream);
    convw_hist<<<256 + NEB, 256, 0, stream>>>(W1, W2, W1t, W2t, col, cnt);
    scan1_kernel<<<NB, 256, 0, stream>>>(cnt, bsum);
    scan23_kernel<<<NB, 256, 0, stream>>>(cnt, bsum, row_off, cursor, dinv);
    gemm1_scatter<<<G1TILES + NEB, 256, 0, stream>>>(x, W1t, dinv, Hb, G1TILES,
                                                     row, col, cursor, csr);
    agg256_bf<<<(NN + 7) / 8, 256, 0, stream>>>(Hb, row_off, csr, dinv, b1, H2b);
    {
      dim3 grid(OUT_C / 128, (NN + 127) / 128);
      gemm_mfma2<<<grid, 256, 0, stream>>>(H2b, W2t, dinv, H3b);
    }
    agg128_bf<<<(NN + 15) / 16, 256, 0, stream>>>(H3b, row_off, csr, dinv, b2, out);
  }
}